// Round 1
// baseline (706.394 us; speedup 1.0000x reference)
//
#include <hip/hip_runtime.h>
#include <math.h>

#define N_NODES 100000
#define N_EDGES 3200000
#define F_IN 128
#define HID 16
#define C_OUT 10
#define WIN 256       // nodes per window
#define NDIG 391      // ceil(N_NODES/WIN)
#define PNB2 500      // partition blocks (EPB*PNB2 = N_EDGES exact)
#define EPB 6400      // edges per partition block; 16B-aligned slices
#define SCN (NDIG * PNB2)   // 195500
#define SB1 764       // ceil(SCN/256)
#define AP1 17        // padded LDS row stride for HID accumulate (odd -> bank spread)
#define AP2 11        // padded LDS row stride for C_OUT accumulate

typedef unsigned short u16;
typedef unsigned int u32;

__device__ __forceinline__ float bf2f(u16 u) {
    return __uint_as_float(((u32)u) << 16);
}
__device__ __forceinline__ u16 f2bf(float f) {
    u32 x = __float_as_uint(f);
    u32 r = (x + 0x7fffu + ((x >> 16) & 1u)) >> 16;  // round-nearest-even
    return (u16)r;
}
__device__ __forceinline__ void acc8(float* a, uint4 w) {
    a[0] += bf2f((u16)(w.x & 0xffff)); a[1] += bf2f((u16)(w.x >> 16));
    a[2] += bf2f((u16)(w.y & 0xffff)); a[3] += bf2f((u16)(w.y >> 16));
    a[4] += bf2f((u16)(w.z & 0xffff)); a[5] += bf2f((u16)(w.z >> 16));
    a[6] += bf2f((u16)(w.w & 0xffff)); a[7] += bf2f((u16)(w.w >> 16));
}
// 8 fire-and-forget LDS float atomics (ds_add_f32) from one packed uint4
__device__ __forceinline__ void atom8(float* a, uint4 w) {
    atomicAdd(a + 0, bf2f((u16)(w.x & 0xffff)));
    atomicAdd(a + 1, bf2f((u16)(w.x >> 16)));
    atomicAdd(a + 2, bf2f((u16)(w.y & 0xffff)));
    atomicAdd(a + 3, bf2f((u16)(w.y >> 16)));
    atomicAdd(a + 4, bf2f((u16)(w.z & 0xffff)));
    atomicAdd(a + 5, bf2f((u16)(w.z >> 16)));
    atomicAdd(a + 6, bf2f((u16)(w.w & 0xffff)));
    atomicAdd(a + 7, bf2f((u16)(w.w >> 16)));
}

// ---------------- partition 1: per-block window histogram, uint4 edge reads ----------------
__global__ void k_pcnt(const int* __restrict__ col, int* __restrict__ blkhistA) {
    __shared__ int h[NDIG];
    for (int i = threadIdx.x; i < NDIG; i += 256) h[i] = 0;
    __syncthreads();
    const uint4* c4 = (const uint4*)(col + blockIdx.x * EPB);
    for (int i = threadIdx.x; i < EPB / 4; i += 256) {
        uint4 c = c4[i];
        atomicAdd(&h[c.x >> 8], 1);
        atomicAdd(&h[c.y >> 8], 1);
        atomicAdd(&h[c.z >> 8], 1);
        atomicAdd(&h[c.w >> 8], 1);
    }
    __syncthreads();
    for (int d = threadIdx.x; d < NDIG; d += 256)
        blkhistA[d * PNB2 + blockIdx.x] = h[d];  // digit-major, raw (kept)
}

// ---------------- partition 2a: per-256-chunk sums ----------------
__global__ void k_s1(const int* __restrict__ blkhistA, int* __restrict__ psum) {
    __shared__ int sm[256];
    int i = blockIdx.x * 256 + threadIdx.x;
    sm[threadIdx.x] = (i < SCN) ? blkhistA[i] : 0;
    __syncthreads();
    for (int off = 128; off > 0; off >>= 1) {
        if (threadIdx.x < off) sm[threadIdx.x] += sm[threadIdx.x + off];
        __syncthreads();
    }
    if (threadIdx.x == 0) psum[blockIdx.x] = sm[0];
}

// ---------------- partition 2b: chunk scan (redundant per block) + local scan -> blkhistB ----------------
__global__ void k_s3(const int* __restrict__ blkhistA, const int* __restrict__ psum,
                     int* __restrict__ blkhistB) {
    __shared__ int ps[1024];
    __shared__ int sm[256];
    int t = threadIdx.x;
    for (int i = t; i < 1024; i += 256) ps[i] = (i < SB1) ? psum[i] : 0;
    __syncthreads();
    // inclusive Hillis-Steele over 1024 entries, 4 per thread
    for (int off = 1; off < 1024; off <<= 1) {
        int v[4];
#pragma unroll
        for (int j = 0; j < 4; j++) {
            int idx = t + j * 256;
            v[j] = ps[idx] + ((idx >= off) ? ps[idx - off] : 0);
        }
        __syncthreads();
#pragma unroll
        for (int j = 0; j < 4; j++) ps[t + j * 256] = v[j];
        __syncthreads();
    }
    int bpre = (blockIdx.x > 0) ? ps[blockIdx.x - 1] : 0;  // exclusive chunk prefix

    int i = blockIdx.x * 256 + t;
    int v = (i < SCN) ? blkhistA[i] : 0;
    sm[t] = v;
    __syncthreads();
    for (int off = 1; off < 256; off <<= 1) {
        int a = sm[t];
        int b = (t >= off) ? sm[t - off] : 0;
        __syncthreads();
        sm[t] = a + b;
        __syncthreads();
    }
    if (i < SCN) blkhistB[i] = bpre + sm[t] - v;  // exclusive global offset
}

// ---------------- partition 3: LDS-sorted scatter -> run-coalesced staging writes ----------------
// entry: (c & 255) << 17 | src   (8 + 17 = 25 bits).  512 threads/block.
__global__ void __launch_bounds__(512) k_pwrite(
        const int* __restrict__ row, const int* __restrict__ col,
        const int* __restrict__ blkhistA, const int* __restrict__ blkhistB,
        u32* __restrict__ staging) {
    __shared__ u32 sorted[EPB];     // 25600 B
    __shared__ u16 dwin[EPB];       // 12800 B
    __shared__ int gbase[NDIG];
    __shared__ int lbase[NDIG];
    __shared__ int lcur[NDIG];
    __shared__ int scan[512];

    int t = threadIdx.x;
    int b = blockIdx.x;
    int hv = 0;
    if (t < NDIG) {
        hv = blkhistA[t * PNB2 + b];
        gbase[t] = blkhistB[t * PNB2 + b];
        lcur[t] = 0;
    }
    scan[t] = hv;
    __syncthreads();
    for (int off = 1; off < 512; off <<= 1) {
        int v = scan[t];
        int u = (t >= off) ? scan[t - off] : 0;
        __syncthreads();
        scan[t] = v + u;
        __syncthreads();
    }
    if (t < NDIG) lbase[t] = scan[t] - hv;  // exclusive local offset
    __syncthreads();

    const uint4* c4 = (const uint4*)(col + b * EPB);
    const uint4* r4 = (const uint4*)(row + b * EPB);
    for (int i = t; i < EPB / 4; i += 512) {
        uint4 c = c4[i];
        uint4 r = r4[i];
        int d, rank, pos;
        d = (int)(c.x >> 8); rank = atomicAdd(&lcur[d], 1); pos = lbase[d] + rank;
        sorted[pos] = ((c.x & 255u) << 17) | r.x; dwin[pos] = (u16)d;
        d = (int)(c.y >> 8); rank = atomicAdd(&lcur[d], 1); pos = lbase[d] + rank;
        sorted[pos] = ((c.y & 255u) << 17) | r.y; dwin[pos] = (u16)d;
        d = (int)(c.z >> 8); rank = atomicAdd(&lcur[d], 1); pos = lbase[d] + rank;
        sorted[pos] = ((c.z & 255u) << 17) | r.z; dwin[pos] = (u16)d;
        d = (int)(c.w >> 8); rank = atomicAdd(&lcur[d], 1); pos = lbase[d] + rank;
        sorted[pos] = ((c.w & 255u) << 17) | r.w; dwin[pos] = (u16)d;
    }
    __syncthreads();

    for (int i = t; i < EPB; i += 512) {
        int d = dwin[i];
        staging[gbase[d] + (i - lbase[d])] = sorted[i];
    }
}

// ---------------- per-node degree from window-sorted staging -> dis ----------------
__global__ void __launch_bounds__(512) k_deg(
        const u32* __restrict__ staging, const int* __restrict__ blkhistB,
        float* __restrict__ dis) {
    __shared__ int cnt[WIN];
    int w = blockIdx.x;
    int t = threadIdx.x;
    if (t < WIN) cnt[t] = 0;
    __syncthreads();
    int start = blkhistB[w * PNB2];
    int end = (w == NDIG - 1) ? N_EDGES : blkhistB[(w + 1) * PNB2];
    for (int i = start + t; i < end; i += 512)
        atomicAdd(&cnt[staging[i] >> 17], 1);
    __syncthreads();
    int node = w * WIN + t;
    if (t < WIN && node < N_NODES)
        dis[node] = rsqrtf(1.0f + (float)cnt[t]);
}

// ---------------- layer 1 GEMM: h1s = (x @ W1) * dis[node]  (bf16) ----------------
__global__ void k_gemm1(const float* __restrict__ x, const float* __restrict__ W1,
                        const float* __restrict__ dis, u16* __restrict__ h1s) {
    __shared__ float Ws[F_IN * HID];  // 8 KB
    for (int t = threadIdx.x; t < F_IN * HID; t += blockDim.x) Ws[t] = W1[t];
    __syncthreads();

    int node = blockIdx.x * blockDim.x + threadIdx.x;
    if (node >= N_NODES) return;

    float acc[HID];
#pragma unroll
    for (int j = 0; j < HID; j++) acc[j] = 0.f;

    const float4* xr = (const float4*)(x + (size_t)node * F_IN);
#pragma unroll 2
    for (int k4 = 0; k4 < F_IN / 4; k4++) {
        float4 v = xr[k4];
        float xv[4] = {v.x, v.y, v.z, v.w};
#pragma unroll
        for (int kk = 0; kk < 4; kk++) {
            const float4* wr = (const float4*)(Ws + (k4 * 4 + kk) * HID);
            float4 w0 = wr[0], w1 = wr[1], w2 = wr[2], w3 = wr[3];
            float xs = xv[kk];
            acc[0]  += xs * w0.x; acc[1]  += xs * w0.y; acc[2]  += xs * w0.z; acc[3]  += xs * w0.w;
            acc[4]  += xs * w1.x; acc[5]  += xs * w1.y; acc[6]  += xs * w1.z; acc[7]  += xs * w1.w;
            acc[8]  += xs * w2.x; acc[9]  += xs * w2.y; acc[10] += xs * w2.z; acc[11] += xs * w2.w;
            acc[12] += xs * w3.x; acc[13] += xs * w3.y; acc[14] += xs * w3.z; acc[15] += xs * w3.w;
        }
    }

    float d = dis[node];
    u32 p[8];
#pragma unroll
    for (int i = 0; i < 8; i++)
        p[i] = (u32)f2bf(acc[2 * i] * d) | ((u32)f2bf(acc[2 * i + 1] * d) << 16);
    u32* dst = (u32*)(h1s + (size_t)node * HID);
#pragma unroll
    for (int i = 0; i < 8; i++) dst[i] = p[i];
}

// ---------------- gather1 (edge-parallel, LDS atomic accumulate) + fused layer2 -> h2s ----------------
// one block per window; streams window-sorted staging; acc[tgt][feat] in LDS, stride AP1=17
__global__ void __launch_bounds__(512) k_gl1e(
        const int* __restrict__ blkhistB, const u32* __restrict__ staging,
        const float* __restrict__ dis, const u16* __restrict__ h1s,
        const float* __restrict__ b1, const float* __restrict__ W2,
        u16* __restrict__ h2s) {
    __shared__ float acc[WIN * AP1];   // 17408 B
    __shared__ float Ws[HID * C_OUT];
    __shared__ float b1s[HID];
    int t = threadIdx.x;
    int w = blockIdx.x;
    if (t < HID * C_OUT) Ws[t] = W2[t];
    if (t < HID) b1s[t] = b1[t];
    for (int i = t; i < WIN * AP1; i += 512) acc[i] = 0.f;
    __syncthreads();

    int start = blkhistB[w * PNB2];
    int end = (w == NDIG - 1) ? N_EDGES : blkhistB[(w + 1) * PNB2];
    const uint4* hb = (const uint4*)h1s;

    int i = start + t;
    if (i < end) {
        u32 e = staging[i];
        int src = (int)(e & 0x1FFFFu);
        uint4 va = hb[2 * (size_t)src];
        uint4 vb = hb[2 * (size_t)src + 1];
        for (;;) {
            int inext = i + 512;
            bool more = (inext < end);
            u32 en = e; uint4 na = va, nb = vb;
            if (more) {
                en = staging[inext];
                int sn = (int)(en & 0x1FFFFu);
                na = hb[2 * (size_t)sn];
                nb = hb[2 * (size_t)sn + 1];
            }
            float* arow = acc + (e >> 17) * AP1;
            atom8(arow, va);
            atom8(arow + 8, vb);
            if (!more) break;
            i = inext; e = en; va = na; vb = nb;
        }
    }
    __syncthreads();

    if (t < WIN) {
        int node = w * WIN + t;
        if (node < N_NODES) {
            float dc = dis[node];
            float sum[HID];
            const float* arow = acc + t * AP1;
#pragma unroll
            for (int j = 0; j < HID; j++) sum[j] = arow[j];
            acc8(sum, hb[2 * (size_t)node]);       // self loop (pre-scaled)
            acc8(sum + 8, hb[2 * (size_t)node + 1]);
            float h[HID];
#pragma unroll
            for (int j = 0; j < HID; j++)
                h[j] = fmaxf(sum[j] * dc + b1s[j], 0.f);
            float outv[C_OUT];
#pragma unroll
            for (int k = 0; k < C_OUT; k++) {
                float s = 0.f;
#pragma unroll
                for (int j = 0; j < HID; j++) s += h[j] * Ws[j * C_OUT + k];
                outv[k] = s * dc;  // pre-scale for gather2
            }
            uint4 o0, o1;
            o0.x = (u32)f2bf(outv[0]) | ((u32)f2bf(outv[1]) << 16);
            o0.y = (u32)f2bf(outv[2]) | ((u32)f2bf(outv[3]) << 16);
            o0.z = (u32)f2bf(outv[4]) | ((u32)f2bf(outv[5]) << 16);
            o0.w = (u32)f2bf(outv[6]) | ((u32)f2bf(outv[7]) << 16);
            o1.x = (u32)f2bf(outv[8]) | ((u32)f2bf(outv[9]) << 16);
            o1.y = 0u; o1.z = 0u; o1.w = 0u;
            uint4* dst = (uint4*)h2s + 2 * (size_t)node;
            dst[0] = o0; dst[1] = o1;
        }
    }
}

// ---------------- gather2 (edge-parallel, LDS atomic accumulate) + fused log_softmax ----------------
__global__ void __launch_bounds__(512) k_g2e(
        const int* __restrict__ blkhistB, const u32* __restrict__ staging,
        const float* __restrict__ dis, const u16* __restrict__ h2s,
        const float* __restrict__ b2, float* __restrict__ out) {
    __shared__ float acc[WIN * AP2];   // 11264 B
    __shared__ float b2s[C_OUT];
    int t = threadIdx.x;
    int w = blockIdx.x;
    if (t < C_OUT) b2s[t] = b2[t];
    for (int i = t; i < WIN * AP2; i += 512) acc[i] = 0.f;
    __syncthreads();

    int start = blkhistB[w * PNB2];
    int end = (w == NDIG - 1) ? N_EDGES : blkhistB[(w + 1) * PNB2];
    const uint4* hb = (const uint4*)h2s;
    const u32* h32 = (const u32*)h2s;

    int i = start + t;
    if (i < end) {
        u32 e = staging[i];
        int src = (int)(e & 0x1FFFFu);
        uint4 va = hb[2 * (size_t)src];
        u32 vc = h32[(size_t)src * 8 + 4];   // feats 8,9
        for (;;) {
            int inext = i + 512;
            bool more = (inext < end);
            u32 en = e; uint4 na = va; u32 nc = vc;
            if (more) {
                en = staging[inext];
                int sn = (int)(en & 0x1FFFFu);
                na = hb[2 * (size_t)sn];
                nc = h32[(size_t)sn * 8 + 4];
            }
            float* arow = acc + (e >> 17) * AP2;
            atom8(arow, va);
            atomicAdd(arow + 8, bf2f((u16)(vc & 0xffff)));
            atomicAdd(arow + 9, bf2f((u16)(vc >> 16)));
            if (!more) break;
            i = inext; e = en; va = na; vc = nc;
        }
    }
    __syncthreads();

    if (t < WIN) {
        int node = w * WIN + t;
        if (node < N_NODES) {
            float dc = dis[node];
            float sum[C_OUT];
            const float* arow = acc + t * AP2;
#pragma unroll
            for (int k = 0; k < C_OUT; k++) sum[k] = arow[k];
            acc8(sum, hb[2 * (size_t)node]);                    // self feats 0-7
            u32 sc = h32[(size_t)node * 8 + 4];
            sum[8] += bf2f((u16)(sc & 0xffff));
            sum[9] += bf2f((u16)(sc >> 16));
            float lg[C_OUT];
            float m = -1e30f;
#pragma unroll
            for (int k = 0; k < C_OUT; k++) {
                lg[k] = sum[k] * dc + b2s[k];
                m = fmaxf(m, lg[k]);
            }
            float s = 0.f;
#pragma unroll
            for (int k = 0; k < C_OUT; k++) s += expf(lg[k] - m);
            float ls = logf(s) + m;
            float2* dst = (float2*)(out + (size_t)node * C_OUT);
#pragma unroll
            for (int k = 0; k < 5; k++)
                dst[k] = make_float2(lg[2 * k] - ls, lg[2 * k + 1] - ls);
        }
    }
}

// ---------------- launch ----------------
extern "C" void kernel_launch(void* const* d_in, const int* in_sizes, int n_in,
                              void* d_out, int out_size, void* d_ws, size_t ws_size,
                              hipStream_t stream) {
    const float* x  = (const float*)d_in[0];
    const int*   ei = (const int*)d_in[1];
    const float* W1 = (const float*)d_in[2];
    const float* b1 = (const float*)d_in[3];
    const float* W2 = (const float*)d_in[4];
    const float* b2 = (const float*)d_in[5];
    float* out = (float*)d_out;

    const int* row = ei;            // sources
    const int* col = ei + N_EDGES;  // targets

    char* ws = (char*)d_ws;
    float* dis      = (float*)(ws);                   // 400000 B
    int*   blkhistA = (int*)(ws + 800016);            // raw hist (padded SB1*256 ints)
    int*   blkhistB = (int*)(ws + 1582352);           // scanned
    int*   psum     = (int*)(ws + 2364688);           // 764 ints (raw chunk sums)
    u32*   staging  = (u32*)(ws + 2367744);           // 12.8 MB (16B aligned), window-sorted
    u16*   h1s      = (u16*)(ws + 15167744);          // 3.2 MB (16B aligned)
    u16*   h2s      = (u16*)(ws + 18367744);          // 3.2 MB (separate: gl1e reads h1s while writing h2s)

    const int B = 256;
    int gN  = (N_NODES + B - 1) / B;            // 391

    // deterministic window partition (zero global atomics); no per-node CSR needed anymore
    k_pcnt  <<<PNB2, B, 0, stream>>>(col, blkhistA);
    k_s1    <<<SB1, B, 0, stream>>>(blkhistA, psum);
    k_s3    <<<SB1, B, 0, stream>>>(blkhistA, psum, blkhistB);
    k_pwrite<<<PNB2, 512, 0, stream>>>(row, col, blkhistA, blkhistB, staging);
    k_deg   <<<NDIG, 512, 0, stream>>>(staging, blkhistB, dis);
    // dense pipeline (layer2 fused into gather1; softmax fused into gather2)
    k_gemm1 <<<gN, B, 0, stream>>>(x, W1, dis, h1s);
    k_gl1e  <<<NDIG, 512, 0, stream>>>(blkhistB, staging, dis, h1s, b1, W2, h2s);
    k_g2e   <<<NDIG, 512, 0, stream>>>(blkhistB, staging, dis, h2s, b2, out);
}

// Round 2
// 222.814 us; speedup vs baseline: 3.1703x; 3.1703x over previous
//
#include <hip/hip_runtime.h>
#include <math.h>

#define N_NODES 100000
#define N_EDGES 3200000
#define F_IN 128
#define HID 16
#define C_OUT 10
#define WIN 256       // nodes per window
#define NDIG 391      // ceil(N_NODES/WIN)
#define PNB2 500      // partition blocks (EPB*PNB2 = N_EDGES exact)
#define EPB 6400      // edges per partition block; 16B-aligned slices
#define SCN (NDIG * PNB2)   // 195500
#define SB1 764       // ceil(SCN/256)
#define MAXE2 20      // per-thread staged entries in k_csr (512 thr; cap 10240 vs mean 8192)

typedef unsigned short u16;
typedef unsigned int u32;

__device__ __forceinline__ float bf2f(u16 u) {
    return __uint_as_float(((u32)u) << 16);
}
__device__ __forceinline__ u16 f2bf(float f) {
    u32 x = __float_as_uint(f);
    u32 r = (x + 0x7fffu + ((x >> 16) & 1u)) >> 16;  // round-nearest-even
    return (u16)r;
}
__device__ __forceinline__ void acc8(float* a, uint4 w) {
    a[0] += bf2f((u16)(w.x & 0xffff)); a[1] += bf2f((u16)(w.x >> 16));
    a[2] += bf2f((u16)(w.y & 0xffff)); a[3] += bf2f((u16)(w.y >> 16));
    a[4] += bf2f((u16)(w.z & 0xffff)); a[5] += bf2f((u16)(w.z >> 16));
    a[6] += bf2f((u16)(w.w & 0xffff)); a[7] += bf2f((u16)(w.w >> 16));
}

// ---------------- partition 1: per-block window histogram, uint4 edge reads ----------------
__global__ void k_pcnt(const int* __restrict__ col, int* __restrict__ blkhistA) {
    __shared__ int h[NDIG];
    for (int i = threadIdx.x; i < NDIG; i += 256) h[i] = 0;
    __syncthreads();
    const uint4* c4 = (const uint4*)(col + blockIdx.x * EPB);
    for (int i = threadIdx.x; i < EPB / 4; i += 256) {
        uint4 c = c4[i];
        atomicAdd(&h[c.x >> 8], 1);
        atomicAdd(&h[c.y >> 8], 1);
        atomicAdd(&h[c.z >> 8], 1);
        atomicAdd(&h[c.w >> 8], 1);
    }
    __syncthreads();
    for (int d = threadIdx.x; d < NDIG; d += 256)
        blkhistA[d * PNB2 + blockIdx.x] = h[d];  // digit-major, raw (kept)
}

// ---------------- partition 2a: per-256-chunk sums ----------------
__global__ void k_s1(const int* __restrict__ blkhistA, int* __restrict__ psum) {
    __shared__ int sm[256];
    int i = blockIdx.x * 256 + threadIdx.x;
    sm[threadIdx.x] = (i < SCN) ? blkhistA[i] : 0;
    __syncthreads();
    for (int off = 128; off > 0; off >>= 1) {
        if (threadIdx.x < off) sm[threadIdx.x] += sm[threadIdx.x + off];
        __syncthreads();
    }
    if (threadIdx.x == 0) psum[blockIdx.x] = sm[0];
}

// ---------------- partition 2b: chunk scan (redundant per block) + local scan -> blkhistB ----------------
__global__ void k_s3(const int* __restrict__ blkhistA, const int* __restrict__ psum,
                     int* __restrict__ blkhistB) {
    __shared__ int ps[1024];
    __shared__ int sm[256];
    int t = threadIdx.x;
    for (int i = t; i < 1024; i += 256) ps[i] = (i < SB1) ? psum[i] : 0;
    __syncthreads();
    // inclusive Hillis-Steele over 1024 entries, 4 per thread
    for (int off = 1; off < 1024; off <<= 1) {
        int v[4];
#pragma unroll
        for (int j = 0; j < 4; j++) {
            int idx = t + j * 256;
            v[j] = ps[idx] + ((idx >= off) ? ps[idx - off] : 0);
        }
        __syncthreads();
#pragma unroll
        for (int j = 0; j < 4; j++) ps[t + j * 256] = v[j];
        __syncthreads();
    }
    int bpre = (blockIdx.x > 0) ? ps[blockIdx.x - 1] : 0;  // exclusive chunk prefix

    int i = blockIdx.x * 256 + t;
    int v = (i < SCN) ? blkhistA[i] : 0;
    sm[t] = v;
    __syncthreads();
    for (int off = 1; off < 256; off <<= 1) {
        int a = sm[t];
        int b = (t >= off) ? sm[t - off] : 0;
        __syncthreads();
        sm[t] = a + b;
        __syncthreads();
    }
    if (i < SCN) blkhistB[i] = bpre + sm[t] - v;  // exclusive global offset
}

// ---------------- partition 3: LDS-sorted scatter -> run-coalesced staging writes ----------------
// entry: (c & 255) << 17 | src   (8 + 17 = 25 bits).  512 threads/block.
__global__ void __launch_bounds__(512) k_pwrite(
        const int* __restrict__ row, const int* __restrict__ col,
        const int* __restrict__ blkhistA, const int* __restrict__ blkhistB,
        u32* __restrict__ staging) {
    __shared__ u32 sorted[EPB];     // 25600 B
    __shared__ u16 dwin[EPB];       // 12800 B
    __shared__ int gbase[NDIG];
    __shared__ int lbase[NDIG];
    __shared__ int lcur[NDIG];
    __shared__ int scan[512];

    int t = threadIdx.x;
    int b = blockIdx.x;
    int hv = 0;
    if (t < NDIG) {
        hv = blkhistA[t * PNB2 + b];
        gbase[t] = blkhistB[t * PNB2 + b];
        lcur[t] = 0;
    }
    scan[t] = hv;
    __syncthreads();
    for (int off = 1; off < 512; off <<= 1) {
        int v = scan[t];
        int u = (t >= off) ? scan[t - off] : 0;
        __syncthreads();
        scan[t] = v + u;
        __syncthreads();
    }
    if (t < NDIG) lbase[t] = scan[t] - hv;  // exclusive local offset
    __syncthreads();

    const uint4* c4 = (const uint4*)(col + b * EPB);
    const uint4* r4 = (const uint4*)(row + b * EPB);
    for (int i = t; i < EPB / 4; i += 512) {
        uint4 c = c4[i];
        uint4 r = r4[i];
        int d, rank, pos;
        d = (int)(c.x >> 8); rank = atomicAdd(&lcur[d], 1); pos = lbase[d] + rank;
        sorted[pos] = ((c.x & 255u) << 17) | r.x; dwin[pos] = (u16)d;
        d = (int)(c.y >> 8); rank = atomicAdd(&lcur[d], 1); pos = lbase[d] + rank;
        sorted[pos] = ((c.y & 255u) << 17) | r.y; dwin[pos] = (u16)d;
        d = (int)(c.z >> 8); rank = atomicAdd(&lcur[d], 1); pos = lbase[d] + rank;
        sorted[pos] = ((c.z & 255u) << 17) | r.z; dwin[pos] = (u16)d;
        d = (int)(c.w >> 8); rank = atomicAdd(&lcur[d], 1); pos = lbase[d] + rank;
        sorted[pos] = ((c.w & 255u) << 17) | r.w; dwin[pos] = (u16)d;
    }
    __syncthreads();

    for (int i = t; i < EPB; i += 512) {
        int d = dwin[i];
        staging[gbase[d] + (i - lbase[d])] = sorted[i];
    }
}

// ---------------- node-sort each window IN PLACE; emit offs + dis ----------------
// 512 threads, 20-deep register staging (same 10240 cap, half the VGPR pressure)
__global__ void __launch_bounds__(512) k_csr(
        u32* staging, const int* __restrict__ blkhistB,
        int* __restrict__ offs, float* __restrict__ dis) {
    __shared__ int cnt[WIN];
    __shared__ int base[WIN];
    int w = blockIdx.x;
    int t = threadIdx.x;
    if (t < WIN) cnt[t] = 0;
    __syncthreads();
    int start = blkhistB[w * PNB2];
    int end = (w == NDIG - 1) ? N_EDGES : blkhistB[(w + 1) * PNB2];
    u32 buf[MAXE2];
    int n = 0;
#pragma unroll
    for (int k = 0; k < MAXE2; k++) {
        int i = start + k * 512 + t;
        if (i < end) {
            u32 e = staging[i];
            buf[k] = e;
            n = k + 1;
            atomicAdd(&cnt[e >> 17], 1);  // LDS atomic
        }
    }
    __syncthreads();
    if (t < WIN) base[t] = cnt[t];
    __syncthreads();
    for (int off = 1; off < WIN; off <<= 1) {
        int v = 0;
        if (t < WIN) {
            v = base[t];
            if (t >= off) v += base[t - off];
        }
        __syncthreads();
        if (t < WIN) base[t] = v;
        __syncthreads();
    }
    if (t < WIN) {
        int excl = base[t] - cnt[t];
        base[t] = excl;
        int node = w * WIN + t;
        if (node < N_NODES) {
            offs[node] = start + excl;
            dis[node] = rsqrtf(1.0f + (float)cnt[t]);
        }
    }
    if (w == 0 && t == 0) offs[N_NODES] = N_EDGES;
    __syncthreads();
    if (t < WIN) cnt[t] = 0;  // reuse as cursor
    __syncthreads();
#pragma unroll
    for (int k = 0; k < MAXE2; k++) {
        if (k < n) {
            u32 e = buf[k];
            int cl = (int)(e >> 17);
            int rank = atomicAdd(&cnt[cl], 1);  // LDS atomic
            staging[start + base[cl] + rank] = e;
        }
    }
}

// ---------------- layer 1 GEMM: h1s = (x @ W1) * dis[node]  (bf16) ----------------
__global__ void k_gemm1(const float* __restrict__ x, const float* __restrict__ W1,
                        const float* __restrict__ dis, u16* __restrict__ h1s) {
    __shared__ float Ws[F_IN * HID];  // 8 KB
    for (int t = threadIdx.x; t < F_IN * HID; t += blockDim.x) Ws[t] = W1[t];
    __syncthreads();

    int node = blockIdx.x * blockDim.x + threadIdx.x;
    if (node >= N_NODES) return;

    float acc[HID];
#pragma unroll
    for (int j = 0; j < HID; j++) acc[j] = 0.f;

    const float4* xr = (const float4*)(x + (size_t)node * F_IN);
#pragma unroll 2
    for (int k4 = 0; k4 < F_IN / 4; k4++) {
        float4 v = xr[k4];
        float xv[4] = {v.x, v.y, v.z, v.w};
#pragma unroll
        for (int kk = 0; kk < 4; kk++) {
            const float4* wr = (const float4*)(Ws + (k4 * 4 + kk) * HID);
            float4 w0 = wr[0], w1 = wr[1], w2 = wr[2], w3 = wr[3];
            float xs = xv[kk];
            acc[0]  += xs * w0.x; acc[1]  += xs * w0.y; acc[2]  += xs * w0.z; acc[3]  += xs * w0.w;
            acc[4]  += xs * w1.x; acc[5]  += xs * w1.y; acc[6]  += xs * w1.z; acc[7]  += xs * w1.w;
            acc[8]  += xs * w2.x; acc[9]  += xs * w2.y; acc[10] += xs * w2.z; acc[11] += xs * w2.w;
            acc[12] += xs * w3.x; acc[13] += xs * w3.y; acc[14] += xs * w3.z; acc[15] += xs * w3.w;
        }
    }

    float d = dis[node];
    u32 p[8];
#pragma unroll
    for (int i = 0; i < 8; i++)
        p[i] = (u32)f2bf(acc[2 * i] * d) | ((u32)f2bf(acc[2 * i + 1] * d) << 16);
    u32* dst = (u32*)(h1s + (size_t)node * HID);
#pragma unroll
    for (int i = 0; i < 8; i++) dst[i] = p[i];
}

// ---------------- gather1 + layer2 fused: 4 lanes/node (feat-half x edge-half) ----------------
// q = t&3: half = q>>1 (feature half), eh = q&1 (edge half). agg1 never hits memory.
__global__ void k_gl1(const int* __restrict__ offs, const u32* __restrict__ csr,
                      const float* __restrict__ dis, const u16* __restrict__ h1s,
                      const float* __restrict__ b1, const float* __restrict__ W2,
                      u16* __restrict__ h2s) {
    __shared__ float Ws[HID * C_OUT];
    __shared__ float b1s[HID];
    if (threadIdx.x < HID * C_OUT) Ws[threadIdx.x] = W2[threadIdx.x];
    if (threadIdx.x < HID) b1s[threadIdx.x] = b1[threadIdx.x];
    __syncthreads();

    int t = blockIdx.x * 256 + threadIdx.x;
    if (t >= N_NODES * 4) return;
    int node = t >> 2;
    int q = t & 3;
    int half = q >> 1;
    int eh = q & 1;
    const uint4* hb = (const uint4*)h1s;
    float a[8] = {0.f, 0.f, 0.f, 0.f, 0.f, 0.f, 0.f, 0.f};
    if (eh == 0) acc8(a, hb[(size_t)node * 2 + half]);  // self loop once per half-pair
    int o = offs[node + half];             // q0,q1 load offs[node]; q2,q3 offs[node+1]
    int oo = __shfl_xor(o, 2);
    int s0 = half ? oo : o;
    int s1 = half ? o : oo;
    int mid = s0 + ((s1 - s0) >> 1);
    int lo = eh ? mid : s0;
    int hi = eh ? s1 : mid;
    int j = lo;
    for (; j < hi && (j & 3); j++)
        acc8(a, hb[(size_t)(csr[j] & 0x1FFFFu) * 2 + half]);
    for (; j + 4 <= hi; j += 4) {
        uint4 ss = *(const uint4*)(csr + j);
        uint4 w0 = hb[(size_t)(ss.x & 0x1FFFFu) * 2 + half];
        uint4 w1 = hb[(size_t)(ss.y & 0x1FFFFu) * 2 + half];
        uint4 w2 = hb[(size_t)(ss.z & 0x1FFFFu) * 2 + half];
        uint4 w3 = hb[(size_t)(ss.w & 0x1FFFFu) * 2 + half];
        acc8(a, w0); acc8(a, w1); acc8(a, w2); acc8(a, w3);
    }
    for (; j < hi; j++)
        acc8(a, hb[(size_t)(csr[j] & 0x1FFFFu) * 2 + half]);

    // combine edge halves within the (node,half) pair
#pragma unroll
    for (int k = 0; k < 8; k++) a[k] += __shfl_xor(a[k], 1);

    float dc = dis[node];
    float own[8], oth[8];
#pragma unroll
    for (int k = 0; k < 8; k++) own[k] = a[k] * dc;      // agg1 feats half*8+k (fp32)
#pragma unroll
    for (int k = 0; k < 8; k++) oth[k] = __shfl_xor(own[k], 2);
    float h[16];
#pragma unroll
    for (int k = 0; k < 8; k++) {
        h[k]     = half ? oth[k] : own[k];
        h[8 + k] = half ? own[k] : oth[k];
    }
#pragma unroll
    for (int jj = 0; jj < 16; jj++) h[jj] = fmaxf(h[jj] + b1s[jj], 0.f);

    int nf = half ? 2 : 8;
    float outv[8];
#pragma unroll
    for (int k = 0; k < 8; k++) {
        float s = 0.f;
        if (k < nf) {
            int kk = half * 8 + k;
#pragma unroll
            for (int jj = 0; jj < 16; jj++) s += h[jj] * Ws[jj * C_OUT + kk];
        }
        outv[k] = s * dc;  // pre-scale for gather2
    }
    if (eh == 0) {
        uint4 ov;
        ov.x = (u32)f2bf(outv[0]) | ((u32)f2bf(outv[1]) << 16);
        ov.y = half ? 0u : ((u32)f2bf(outv[2]) | ((u32)f2bf(outv[3]) << 16));
        ov.z = half ? 0u : ((u32)f2bf(outv[4]) | ((u32)f2bf(outv[5]) << 16));
        ov.w = half ? 0u : ((u32)f2bf(outv[6]) | ((u32)f2bf(outv[7]) << 16));
        ((uint4*)h2s)[(size_t)node * 2 + half] = ov;
    }
}

// ---------------- gather layer 2 + fused log_softmax: 4 lanes/node ----------------
__global__ void k_gather2(const int* __restrict__ offs, const u32* __restrict__ csr,
                          const float* __restrict__ dis, const u16* __restrict__ h2s,
                          const float* __restrict__ b2, float* __restrict__ out) {
    __shared__ float b2s[C_OUT];
    if (threadIdx.x < C_OUT) b2s[threadIdx.x] = b2[threadIdx.x];
    __syncthreads();

    int t = blockIdx.x * 256 + threadIdx.x;
    if (t >= N_NODES * 4) return;
    int node = t >> 2;
    int q = t & 3;
    int half = q >> 1;  // half0: feats 0-7, half1: feats 8,9 (+6 zero pads)
    int eh = q & 1;
    const uint4* hb = (const uint4*)h2s;
    float a[8] = {0.f, 0.f, 0.f, 0.f, 0.f, 0.f, 0.f, 0.f};
    if (eh == 0) acc8(a, hb[(size_t)node * 2 + half]);  // self loop once
    int o = offs[node + half];
    int oo = __shfl_xor(o, 2);
    int s0 = half ? oo : o;
    int s1 = half ? o : oo;
    int mid = s0 + ((s1 - s0) >> 1);
    int lo = eh ? mid : s0;
    int hi = eh ? s1 : mid;
    int j = lo;
    for (; j < hi && (j & 3); j++)
        acc8(a, hb[(size_t)(csr[j] & 0x1FFFFu) * 2 + half]);
    for (; j + 4 <= hi; j += 4) {
        uint4 ss = *(const uint4*)(csr + j);
        uint4 w0 = hb[(size_t)(ss.x & 0x1FFFFu) * 2 + half];
        uint4 w1 = hb[(size_t)(ss.y & 0x1FFFFu) * 2 + half];
        uint4 w2 = hb[(size_t)(ss.z & 0x1FFFFu) * 2 + half];
        uint4 w3 = hb[(size_t)(ss.w & 0x1FFFFu) * 2 + half];
        acc8(a, w0); acc8(a, w1); acc8(a, w2); acc8(a, w3);
    }
    for (; j < hi; j++)
        acc8(a, hb[(size_t)(csr[j] & 0x1FFFFu) * 2 + half]);

#pragma unroll
    for (int k = 0; k < 8; k++) a[k] += __shfl_xor(a[k], 1);  // combine edge halves

    float dc = dis[node];
    int nf = half ? 2 : 8;
    float lg[8];
    float m = -1e30f;
#pragma unroll
    for (int k = 0; k < 8; k++) {
        lg[k] = a[k] * dc + b2s[(half * 8 + k) % C_OUT];
        if (k < nf) m = fmaxf(m, lg[k]);
    }
    m = fmaxf(m, __shfl_xor(m, 2));          // pair max over 10 logits
    float s = 0.f;
#pragma unroll
    for (int k = 0; k < 8; k++)
        if (k < nf) s += expf(lg[k] - m);
    s += __shfl_xor(s, 2);                   // pair sum
    float ls = logf(s) + m;
    if (eh == 0) {
        float* dst = out + (size_t)node * C_OUT + half * 8;
        if (half == 0) {
#pragma unroll
            for (int i = 0; i < 4; i++)
                *(float2*)(dst + 2 * i) = make_float2(lg[2 * i] - ls, lg[2 * i + 1] - ls);
        } else {
            *(float2*)dst = make_float2(lg[0] - ls, lg[1] - ls);
        }
    }
}

// ---------------- launch ----------------
extern "C" void kernel_launch(void* const* d_in, const int* in_sizes, int n_in,
                              void* d_out, int out_size, void* d_ws, size_t ws_size,
                              hipStream_t stream) {
    const float* x  = (const float*)d_in[0];
    const int*   ei = (const int*)d_in[1];
    const float* W1 = (const float*)d_in[2];
    const float* b1 = (const float*)d_in[3];
    const float* W2 = (const float*)d_in[4];
    const float* b2 = (const float*)d_in[5];
    float* out = (float*)d_out;

    const int* row = ei;            // sources
    const int* col = ei + N_EDGES;  // targets

    char* ws = (char*)d_ws;
    float* dis      = (float*)(ws);                   // 400000 B
    int*   offs     = (int*)(ws + 400000);            // N+1 ints
    int*   blkhistA = (int*)(ws + 800016);            // raw hist (padded SB1*256 ints)
    int*   blkhistB = (int*)(ws + 1582352);           // scanned
    int*   psum     = (int*)(ws + 2364688);           // 764 ints (raw chunk sums)
    u32*   staging  = (u32*)(ws + 2367744);           // 12.8 MB (16B aligned), becomes CSR
    u16*   h1s      = (u16*)(ws + 15167744);          // 3.2 MB (16B aligned)
    u16*   h2s      = (u16*)(ws + 18367744);          // 3.2 MB (separate: gl1 reads h1s while writing h2s)

    const int B = 256;
    int gN  = (N_NODES + B - 1) / B;            // 391
    int gN4 = (N_NODES * 4 + B - 1) / B;        // 1563

    // deterministic window partition + in-window node sort (zero global atomics)
    k_pcnt  <<<PNB2, B, 0, stream>>>(col, blkhistA);
    k_s1    <<<SB1, B, 0, stream>>>(blkhistA, psum);
    k_s3    <<<SB1, B, 0, stream>>>(blkhistA, psum, blkhistB);
    k_pwrite<<<PNB2, 512, 0, stream>>>(row, col, blkhistA, blkhistB, staging);
    k_csr   <<<NDIG, 512, 0, stream>>>(staging, blkhistB, offs, dis);
    // dense pipeline (layer2 fused into gather1; softmax fused into gather2)
    k_gemm1 <<<gN, B, 0, stream>>>(x, W1, dis, h1s);
    k_gl1   <<<gN4, B, 0, stream>>>(offs, staging, dis, h1s, b1, W2, h2s);
    k_gather2<<<gN4, B, 0, stream>>>(offs, staging, dis, h2s, b2, out);
}

// Round 3
// 212.198 us; speedup vs baseline: 3.3289x; 1.0500x over previous
//
#include <hip/hip_runtime.h>
#include <math.h>

#define N_NODES 100000
#define N_EDGES 3200000
#define F_IN 128
#define HID 16
#define C_OUT 10
#define WIN 256       // nodes per window
#define NDIG 391      // ceil(N_NODES/WIN)
#define PNB2 500      // partition blocks (EPB*PNB2 = N_EDGES exact)
#define EPB 6400      // edges per partition block; 16B-aligned slices
#define SCN (NDIG * PNB2)   // 195500
#define SB1 764       // ceil(SCN/256)
#define MAXE2 20      // per-thread staged entries in k_csr (512 thr; cap 10240 vs mean 8192)
#define CSRLDS 10240  // LDS sort buffer (u32) per window

typedef unsigned short u16;
typedef unsigned int u32;

__device__ __forceinline__ float bf2f(u16 u) {
    return __uint_as_float(((u32)u) << 16);
}
__device__ __forceinline__ u16 f2bf(float f) {
    u32 x = __float_as_uint(f);
    u32 r = (x + 0x7fffu + ((x >> 16) & 1u)) >> 16;  // round-nearest-even
    return (u16)r;
}
__device__ __forceinline__ void acc8(float* a, uint4 w) {
    a[0] += bf2f((u16)(w.x & 0xffff)); a[1] += bf2f((u16)(w.x >> 16));
    a[2] += bf2f((u16)(w.y & 0xffff)); a[3] += bf2f((u16)(w.y >> 16));
    a[4] += bf2f((u16)(w.z & 0xffff)); a[5] += bf2f((u16)(w.z >> 16));
    a[6] += bf2f((u16)(w.w & 0xffff)); a[7] += bf2f((u16)(w.w >> 16));
}

// ---------------- partition 1: per-block window histogram, uint4 edge reads ----------------
__global__ void k_pcnt(const int* __restrict__ col, int* __restrict__ blkhistA) {
    __shared__ int h[NDIG];
    for (int i = threadIdx.x; i < NDIG; i += 256) h[i] = 0;
    __syncthreads();
    const uint4* c4 = (const uint4*)(col + blockIdx.x * EPB);
    for (int i = threadIdx.x; i < EPB / 4; i += 256) {
        uint4 c = c4[i];
        atomicAdd(&h[c.x >> 8], 1);
        atomicAdd(&h[c.y >> 8], 1);
        atomicAdd(&h[c.z >> 8], 1);
        atomicAdd(&h[c.w >> 8], 1);
    }
    __syncthreads();
    for (int d = threadIdx.x; d < NDIG; d += 256)
        blkhistA[d * PNB2 + blockIdx.x] = h[d];  // digit-major, raw (kept)
}

// ---------------- partition 2a: per-256-chunk sums ----------------
__global__ void k_s1(const int* __restrict__ blkhistA, int* __restrict__ psum) {
    __shared__ int sm[256];
    int i = blockIdx.x * 256 + threadIdx.x;
    sm[threadIdx.x] = (i < SCN) ? blkhistA[i] : 0;
    __syncthreads();
    for (int off = 128; off > 0; off >>= 1) {
        if (threadIdx.x < off) sm[threadIdx.x] += sm[threadIdx.x + off];
        __syncthreads();
    }
    if (threadIdx.x == 0) psum[blockIdx.x] = sm[0];
}

// ---------------- partition 2b: chunk scan (redundant per block) + local scan -> blkhistB ----------------
__global__ void k_s3(const int* __restrict__ blkhistA, const int* __restrict__ psum,
                     int* __restrict__ blkhistB) {
    __shared__ int ps[1024];
    __shared__ int sm[256];
    int t = threadIdx.x;
    for (int i = t; i < 1024; i += 256) ps[i] = (i < SB1) ? psum[i] : 0;
    __syncthreads();
    // inclusive Hillis-Steele over 1024 entries, 4 per thread
    for (int off = 1; off < 1024; off <<= 1) {
        int v[4];
#pragma unroll
        for (int j = 0; j < 4; j++) {
            int idx = t + j * 256;
            v[j] = ps[idx] + ((idx >= off) ? ps[idx - off] : 0);
        }
        __syncthreads();
#pragma unroll
        for (int j = 0; j < 4; j++) ps[t + j * 256] = v[j];
        __syncthreads();
    }
    int bpre = (blockIdx.x > 0) ? ps[blockIdx.x - 1] : 0;  // exclusive chunk prefix

    int i = blockIdx.x * 256 + t;
    int v = (i < SCN) ? blkhistA[i] : 0;
    sm[t] = v;
    __syncthreads();
    for (int off = 1; off < 256; off <<= 1) {
        int a = sm[t];
        int b = (t >= off) ? sm[t - off] : 0;
        __syncthreads();
        sm[t] = a + b;
        __syncthreads();
    }
    if (i < SCN) blkhistB[i] = bpre + sm[t] - v;  // exclusive global offset
}

// ---------------- partition 3: LDS-sorted scatter -> run-coalesced staging writes ----------------
// entry: (c & 255) << 17 | src   (8 + 17 = 25 bits).  512 threads/block.
__global__ void __launch_bounds__(512) k_pwrite(
        const int* __restrict__ row, const int* __restrict__ col,
        const int* __restrict__ blkhistA, const int* __restrict__ blkhistB,
        u32* __restrict__ staging) {
    __shared__ u32 sorted[EPB];     // 25600 B
    __shared__ u16 dwin[EPB];       // 12800 B
    __shared__ int gbase[NDIG];
    __shared__ int lbase[NDIG];
    __shared__ int lcur[NDIG];
    __shared__ int scan[512];

    int t = threadIdx.x;
    int b = blockIdx.x;
    int hv = 0;
    if (t < NDIG) {
        hv = blkhistA[t * PNB2 + b];
        gbase[t] = blkhistB[t * PNB2 + b];
        lcur[t] = 0;
    }
    scan[t] = hv;
    __syncthreads();
    for (int off = 1; off < 512; off <<= 1) {
        int v = scan[t];
        int u = (t >= off) ? scan[t - off] : 0;
        __syncthreads();
        scan[t] = v + u;
        __syncthreads();
    }
    if (t < NDIG) lbase[t] = scan[t] - hv;  // exclusive local offset
    __syncthreads();

    const uint4* c4 = (const uint4*)(col + b * EPB);
    const uint4* r4 = (const uint4*)(row + b * EPB);
    for (int i = t; i < EPB / 4; i += 512) {
        uint4 c = c4[i];
        uint4 r = r4[i];
        int d, rank, pos;
        d = (int)(c.x >> 8); rank = atomicAdd(&lcur[d], 1); pos = lbase[d] + rank;
        sorted[pos] = ((c.x & 255u) << 17) | r.x; dwin[pos] = (u16)d;
        d = (int)(c.y >> 8); rank = atomicAdd(&lcur[d], 1); pos = lbase[d] + rank;
        sorted[pos] = ((c.y & 255u) << 17) | r.y; dwin[pos] = (u16)d;
        d = (int)(c.z >> 8); rank = atomicAdd(&lcur[d], 1); pos = lbase[d] + rank;
        sorted[pos] = ((c.z & 255u) << 17) | r.z; dwin[pos] = (u16)d;
        d = (int)(c.w >> 8); rank = atomicAdd(&lcur[d], 1); pos = lbase[d] + rank;
        sorted[pos] = ((c.w & 255u) << 17) | r.w; dwin[pos] = (u16)d;
    }
    __syncthreads();

    for (int i = t; i < EPB; i += 512) {
        int d = dwin[i];
        staging[gbase[d] + (i - lbase[d])] = sorted[i];
    }
}

// ---------------- node-sort each window via LDS scatter; COALESCED write-back ----------------
__global__ void __launch_bounds__(512) k_csr(
        u32* staging, const int* __restrict__ blkhistB,
        int* __restrict__ offs, float* __restrict__ dis) {
    __shared__ u32 sorted[CSRLDS];  // 40 KB
    __shared__ int cnt[WIN];
    __shared__ int base[WIN];
    int w = blockIdx.x;
    int t = threadIdx.x;
    if (t < WIN) cnt[t] = 0;
    __syncthreads();
    int start = blkhistB[w * PNB2];
    int end = (w == NDIG - 1) ? N_EDGES : blkhistB[(w + 1) * PNB2];
    int m = end - start;
    u32 buf[MAXE2];
    int n = 0;
#pragma unroll
    for (int k = 0; k < MAXE2; k++) {
        int i = k * 512 + t;
        if (i < m) {
            u32 e = staging[start + i];
            buf[k] = e;
            n = k + 1;
            atomicAdd(&cnt[e >> 17], 1);  // LDS atomic
        }
    }
    __syncthreads();
    if (t < WIN) base[t] = cnt[t];
    __syncthreads();
    for (int off = 1; off < WIN; off <<= 1) {
        int v = 0;
        if (t < WIN) {
            v = base[t];
            if (t >= off) v += base[t - off];
        }
        __syncthreads();
        if (t < WIN) base[t] = v;
        __syncthreads();
    }
    if (t < WIN) {
        int excl = base[t] - cnt[t];
        base[t] = excl;  // becomes scatter cursor
        int node = w * WIN + t;
        if (node < N_NODES) {
            offs[node] = start + excl;
            dis[node] = rsqrtf(1.0f + (float)cnt[t]);
        }
    }
    if (w == 0 && t == 0) offs[N_NODES] = N_EDGES;
    __syncthreads();
#pragma unroll
    for (int k = 0; k < MAXE2; k++) {
        if (k < n) {
            u32 e = buf[k];
            int pos = atomicAdd(&base[(int)(e >> 17)], 1);  // LDS atomic rank
            sorted[pos] = e;                                 // LDS scatter
        }
    }
    __syncthreads();
    for (int i = t; i < m; i += 512)
        staging[start + i] = sorted[i];  // coalesced linear write-back
}

// ---------------- layer 1 GEMM: h1s = (x @ W1) * dis[node]  (bf16) ----------------
__global__ void k_gemm1(const float* __restrict__ x, const float* __restrict__ W1,
                        const float* __restrict__ dis, u16* __restrict__ h1s) {
    __shared__ float Ws[F_IN * HID];  // 8 KB
    for (int t = threadIdx.x; t < F_IN * HID; t += blockDim.x) Ws[t] = W1[t];
    __syncthreads();

    int node = blockIdx.x * blockDim.x + threadIdx.x;
    if (node >= N_NODES) return;

    float acc[HID];
#pragma unroll
    for (int j = 0; j < HID; j++) acc[j] = 0.f;

    const float4* xr = (const float4*)(x + (size_t)node * F_IN);
#pragma unroll 2
    for (int k4 = 0; k4 < F_IN / 4; k4++) {
        float4 v = xr[k4];
        float xv[4] = {v.x, v.y, v.z, v.w};
#pragma unroll
        for (int kk = 0; kk < 4; kk++) {
            const float4* wr = (const float4*)(Ws + (k4 * 4 + kk) * HID);
            float4 w0 = wr[0], w1 = wr[1], w2 = wr[2], w3 = wr[3];
            float xs = xv[kk];
            acc[0]  += xs * w0.x; acc[1]  += xs * w0.y; acc[2]  += xs * w0.z; acc[3]  += xs * w0.w;
            acc[4]  += xs * w1.x; acc[5]  += xs * w1.y; acc[6]  += xs * w1.z; acc[7]  += xs * w1.w;
            acc[8]  += xs * w2.x; acc[9]  += xs * w2.y; acc[10] += xs * w2.z; acc[11] += xs * w2.w;
            acc[12] += xs * w3.x; acc[13] += xs * w3.y; acc[14] += xs * w3.z; acc[15] += xs * w3.w;
        }
    }

    float d = dis[node];
    u32 p[8];
#pragma unroll
    for (int i = 0; i < 8; i++)
        p[i] = (u32)f2bf(acc[2 * i] * d) | ((u32)f2bf(acc[2 * i + 1] * d) << 16);
    u32* dst = (u32*)(h1s + (size_t)node * HID);
#pragma unroll
    for (int i = 0; i < 8; i++) dst[i] = p[i];
}

// ---------------- gather1 + layer2 fused: 8 lanes/node (feat-half x edge-quarter) ----------------
// q = t&7: half = q>>2 (feature half), eq = q&3 (edge quarter).
__global__ void k_gl1(const int* __restrict__ offs, const u32* __restrict__ csr,
                      const float* __restrict__ dis, const u16* __restrict__ h1s,
                      const float* __restrict__ b1, const float* __restrict__ W2,
                      u16* __restrict__ h2s) {
    __shared__ float Ws[HID * C_OUT];
    __shared__ float b1s[HID];
    if (threadIdx.x < HID * C_OUT) Ws[threadIdx.x] = W2[threadIdx.x];
    if (threadIdx.x < HID) b1s[threadIdx.x] = b1[threadIdx.x];
    __syncthreads();

    int t = blockIdx.x * 256 + threadIdx.x;
    if (t >= N_NODES * 8) return;
    int node = t >> 3;
    int q = t & 7;
    int half = q >> 2;
    int eq = q & 3;
    const uint4* hb = (const uint4*)h1s;
    float a[8] = {0.f, 0.f, 0.f, 0.f, 0.f, 0.f, 0.f, 0.f};
    if (eq == 0) acc8(a, hb[(size_t)node * 2 + half]);  // self loop once per half
    int o = offs[node + half];             // q<4 load offs[node]; q>=4 offs[node+1]
    int oo = __shfl_xor(o, 4);
    int s0 = half ? oo : o;
    int s1 = half ? o : oo;
    int len = s1 - s0;
    int lo = s0 + ((len * eq) >> 2);
    int hi = s0 + ((len * (eq + 1)) >> 2);
    int j = lo;
    for (; j < hi && (j & 3); j++)
        acc8(a, hb[(size_t)(csr[j] & 0x1FFFFu) * 2 + half]);
    for (; j + 4 <= hi; j += 4) {
        uint4 ss = *(const uint4*)(csr + j);
        uint4 w0 = hb[(size_t)(ss.x & 0x1FFFFu) * 2 + half];
        uint4 w1 = hb[(size_t)(ss.y & 0x1FFFFu) * 2 + half];
        uint4 w2 = hb[(size_t)(ss.z & 0x1FFFFu) * 2 + half];
        uint4 w3 = hb[(size_t)(ss.w & 0x1FFFFu) * 2 + half];
        acc8(a, w0); acc8(a, w1); acc8(a, w2); acc8(a, w3);
    }
    for (; j < hi; j++)
        acc8(a, hb[(size_t)(csr[j] & 0x1FFFFu) * 2 + half]);

    // combine edge quarters within the (node,half) group
#pragma unroll
    for (int k = 0; k < 8; k++) {
        a[k] += __shfl_xor(a[k], 1);
        a[k] += __shfl_xor(a[k], 2);
    }

    float dc = dis[node];
    float own[8], oth[8];
#pragma unroll
    for (int k = 0; k < 8; k++) own[k] = a[k] * dc;      // agg1 feats half*8+k (fp32)
#pragma unroll
    for (int k = 0; k < 8; k++) oth[k] = __shfl_xor(own[k], 4);
    float h[16];
#pragma unroll
    for (int k = 0; k < 8; k++) {
        h[k]     = half ? oth[k] : own[k];
        h[8 + k] = half ? own[k] : oth[k];
    }
#pragma unroll
    for (int jj = 0; jj < 16; jj++) h[jj] = fmaxf(h[jj] + b1s[jj], 0.f);

    int nf = half ? 2 : 8;
    float outv[8];
#pragma unroll
    for (int k = 0; k < 8; k++) {
        float s = 0.f;
        if (k < nf) {
            int kk = half * 8 + k;
#pragma unroll
            for (int jj = 0; jj < 16; jj++) s += h[jj] * Ws[jj * C_OUT + kk];
        }
        outv[k] = s * dc;  // pre-scale for gather2
    }
    if (eq == 0) {
        uint4 ov;
        ov.x = (u32)f2bf(outv[0]) | ((u32)f2bf(outv[1]) << 16);
        ov.y = half ? 0u : ((u32)f2bf(outv[2]) | ((u32)f2bf(outv[3]) << 16));
        ov.z = half ? 0u : ((u32)f2bf(outv[4]) | ((u32)f2bf(outv[5]) << 16));
        ov.w = half ? 0u : ((u32)f2bf(outv[6]) | ((u32)f2bf(outv[7]) << 16));
        ((uint4*)h2s)[(size_t)node * 2 + half] = ov;
    }
}

// ---------------- gather layer 2 + fused log_softmax: 8 lanes/node ----------------
__global__ void k_gather2(const int* __restrict__ offs, const u32* __restrict__ csr,
                          const float* __restrict__ dis, const u16* __restrict__ h2s,
                          const float* __restrict__ b2, float* __restrict__ out) {
    __shared__ float b2s[C_OUT];
    if (threadIdx.x < C_OUT) b2s[threadIdx.x] = b2[threadIdx.x];
    __syncthreads();

    int t = blockIdx.x * 256 + threadIdx.x;
    if (t >= N_NODES * 8) return;
    int node = t >> 3;
    int q = t & 7;
    int half = q >> 2;  // half0: feats 0-7, half1: feats 8,9 (+6 zero pads)
    int eq = q & 3;
    const uint4* hb = (const uint4*)h2s;
    float a[8] = {0.f, 0.f, 0.f, 0.f, 0.f, 0.f, 0.f, 0.f};
    if (eq == 0) acc8(a, hb[(size_t)node * 2 + half]);  // self loop once
    int o = offs[node + half];
    int oo = __shfl_xor(o, 4);
    int s0 = half ? oo : o;
    int s1 = half ? o : oo;
    int len = s1 - s0;
    int lo = s0 + ((len * eq) >> 2);
    int hi = s0 + ((len * (eq + 1)) >> 2);
    int j = lo;
    for (; j < hi && (j & 3); j++)
        acc8(a, hb[(size_t)(csr[j] & 0x1FFFFu) * 2 + half]);
    for (; j + 4 <= hi; j += 4) {
        uint4 ss = *(const uint4*)(csr + j);
        uint4 w0 = hb[(size_t)(ss.x & 0x1FFFFu) * 2 + half];
        uint4 w1 = hb[(size_t)(ss.y & 0x1FFFFu) * 2 + half];
        uint4 w2 = hb[(size_t)(ss.z & 0x1FFFFu) * 2 + half];
        uint4 w3 = hb[(size_t)(ss.w & 0x1FFFFu) * 2 + half];
        acc8(a, w0); acc8(a, w1); acc8(a, w2); acc8(a, w3);
    }
    for (; j < hi; j++)
        acc8(a, hb[(size_t)(csr[j] & 0x1FFFFu) * 2 + half]);

#pragma unroll
    for (int k = 0; k < 8; k++) {
        a[k] += __shfl_xor(a[k], 1);
        a[k] += __shfl_xor(a[k], 2);
    }

    float dc = dis[node];
    int nf = half ? 2 : 8;
    float lg[8];
    float m = -1e30f;
#pragma unroll
    for (int k = 0; k < 8; k++) {
        lg[k] = a[k] * dc + b2s[(half * 8 + k) % C_OUT];
        if (k < nf) m = fmaxf(m, lg[k]);
    }
    m = fmaxf(m, __shfl_xor(m, 4));          // pair max over 10 logits
    float s = 0.f;
#pragma unroll
    for (int k = 0; k < 8; k++)
        if (k < nf) s += expf(lg[k] - m);
    s += __shfl_xor(s, 4);                   // pair sum
    float ls = logf(s) + m;
    if (eq == 0) {
        float* dst = out + (size_t)node * C_OUT + half * 8;
        if (half == 0) {
#pragma unroll
            for (int i = 0; i < 4; i++)
                *(float2*)(dst + 2 * i) = make_float2(lg[2 * i] - ls, lg[2 * i + 1] - ls);
        } else {
            *(float2*)dst = make_float2(lg[0] - ls, lg[1] - ls);
        }
    }
}

// ---------------- launch ----------------
extern "C" void kernel_launch(void* const* d_in, const int* in_sizes, int n_in,
                              void* d_out, int out_size, void* d_ws, size_t ws_size,
                              hipStream_t stream) {
    const float* x  = (const float*)d_in[0];
    const int*   ei = (const int*)d_in[1];
    const float* W1 = (const float*)d_in[2];
    const float* b1 = (const float*)d_in[3];
    const float* W2 = (const float*)d_in[4];
    const float* b2 = (const float*)d_in[5];
    float* out = (float*)d_out;

    const int* row = ei;            // sources
    const int* col = ei + N_EDGES;  // targets

    char* ws = (char*)d_ws;
    float* dis      = (float*)(ws);                   // 400000 B
    int*   offs     = (int*)(ws + 400000);            // N+1 ints
    int*   blkhistA = (int*)(ws + 800016);            // raw hist (padded SB1*256 ints)
    int*   blkhistB = (int*)(ws + 1582352);           // scanned
    int*   psum     = (int*)(ws + 2364688);           // 764 ints (raw chunk sums)
    u32*   staging  = (u32*)(ws + 2367744);           // 12.8 MB (16B aligned), becomes CSR
    u16*   h1s      = (u16*)(ws + 15167744);          // 3.2 MB (16B aligned)
    u16*   h2s      = (u16*)(ws + 18367744);          // 3.2 MB (separate: gl1 reads h1s while writing h2s)

    const int B = 256;
    int gN  = (N_NODES + B - 1) / B;            // 391
    int gN8 = (N_NODES * 8 + B - 1) / B;        // 3125

    // deterministic window partition + in-window node sort (zero global atomics)
    k_pcnt  <<<PNB2, B, 0, stream>>>(col, blkhistA);
    k_s1    <<<SB1, B, 0, stream>>>(blkhistA, psum);
    k_s3    <<<SB1, B, 0, stream>>>(blkhistA, psum, blkhistB);
    k_pwrite<<<PNB2, 512, 0, stream>>>(row, col, blkhistA, blkhistB, staging);
    k_csr   <<<NDIG, 512, 0, stream>>>(staging, blkhistB, offs, dis);
    // dense pipeline (layer2 fused into gather1; softmax fused into gather2)
    k_gemm1 <<<gN, B, 0, stream>>>(x, W1, dis, h1s);
    k_gl1   <<<gN8, B, 0, stream>>>(offs, staging, dis, h1s, b1, W2, h2s);
    k_gather2<<<gN8, B, 0, stream>>>(offs, staging, dis, h2s, b2, out);
}